// Round 10
// baseline (292.162 us; speedup 1.0000x reference)
//
#include <hip/hip_runtime.h>
#include <stdint.h>

// Problem constants (B=64, S=512 -> 32768 tokens)
#define N_TOK 32768
#define DIN   512
#define DFF   1024
#define MPAD  33792   // 32768 + 8*128 worst-case bucket padding

// fp8 rotation convention: within each 128B K-window, row data is rotated by
// (row mod 16)*8 bytes: phys = (k & ~127) + (((k&127) + (row&15)*8) & 127).
// Same permutation on A-rows and B-rows => dot product unchanged. Staging is
// then a linear aligned copy; fragment reads cover all 32 banks (conflict-free).
__device__ __forceinline__ int rotk(int k, int row) {
    return (k & ~127) + (((k & 127) + ((row & 15) << 3)) & 127);
}

typedef __attribute__((ext_vector_type(8))) short bf16x8;
typedef __attribute__((ext_vector_type(4))) float f32x4;
typedef __attribute__((ext_vector_type(8))) int i32x8;
typedef __attribute__((ext_vector_type(16))) float f32x16;

__device__ __forceinline__ unsigned short f2bf(float f) {
    union { float f; unsigned int u; } v; v.f = f;
    unsigned int u = v.u;
    return (unsigned short)((u + 0x7FFFu + ((u >> 16) & 1u)) >> 16);
}
__device__ __forceinline__ float bf2f(unsigned int bits) {
    union { unsigned int u; float f; } v; v.u = bits << 16; return v.f;
}
// pack 4 floats -> 4 OCP e4m3 bytes (hw cvt, saturating)
__device__ __forceinline__ unsigned int pk4_fp8(float a, float b, float c, float d) {
    int v = __builtin_amdgcn_cvt_pk_fp8_f32(a, b, 0, false);
    v = __builtin_amdgcn_cvt_pk_fp8_f32(c, d, v, true);
    return (unsigned int)v;
}
__device__ __forceinline__ unsigned char f2fp8(float a) {
    return (unsigned char)(__builtin_amdgcn_cvt_pk_fp8_f32(a, a, 0, false) & 0xFF);
}

// async 16B global -> LDS (wave-uniform LDS base + lane*16 pattern)
__device__ __forceinline__ void async16(const void* g, void* l) {
    __builtin_amdgcn_global_load_lds(
        (const __attribute__((address_space(1))) void*)g,
        (__attribute__((address_space(3))) void*)l, 16, 0, 0);
}

// ---------------- merged prep: tokens + weights + perm-pad in ONE launch -------
// blocks [0,16384): x -> bf16 Xb + fp8 Xb8 (rotated); blocks 0..63 also
//   histogram their 512 tokens into blockhist[blk][8] (LDS, no global atomics).
// blocks [16384, 26624): weight transpose+cast, z = (b-16384)/1024:
//   z=0: W_pre -> Wp8 [1024][512] fp8 x64 rotated
//   z=1..8: W_types[z-1] -> Wt8 [512][1024] fp8 x64 rotated
//   z=9: W_c1 -> WcT bf16 [512][512] plain
// blocks [26624, 26756): perm[i] = -1 (MPAD entries)
__global__ void prep_kernel(const float* __restrict__ x,
                            unsigned short* __restrict__ Xb,
                            unsigned char* __restrict__ Xb8,
                            const int* __restrict__ types,
                            int* __restrict__ blockhist,
                            const float* __restrict__ Wp,
                            const float* __restrict__ Wt,
                            const float* __restrict__ Wc,
                            unsigned char* __restrict__ Wp8,
                            unsigned char* __restrict__ Wt8,
                            unsigned short* __restrict__ WcT,
                            int* __restrict__ perm) {
    __shared__ float tile[32][33];
    __shared__ int lc[8];
    const int b = blockIdx.x, tid = threadIdx.x;
    if (b < 16384) {
        const int i = b * 1024 + tid * 4;
        float4 v = *(const float4*)(x + i);
        ushort4 o;
        o.x = f2bf(v.x); o.y = f2bf(v.y); o.z = f2bf(v.z); o.w = f2bf(v.w);
        *(ushort4*)(Xb + i) = o;
        const int row = i >> 9;             // DIN=512
        const int k   = i & 511;
        *(unsigned int*)(Xb8 + (size_t)row * DIN + rotk(k, row)) = pk4_fp8(v.x, v.y, v.z, v.w);
        if (b < 64) {
            if (tid < 8) lc[tid] = 0;
            __syncthreads();
            atomicAdd(&lc[types[b * 512 + tid]], 1);
            atomicAdd(&lc[types[b * 512 + 256 + tid]], 1);
            __syncthreads();
            if (tid < 8) blockhist[b * 8 + tid] = lc[tid];
        }
    } else if (b < 26624) {
        const int r = b - 16384;
        const int z = r >> 10;
        const int bx = r & 31, by = (r >> 5) & 31;
        const int tx = tid & 31, ty = tid >> 5;
        const float* s; int K, N;
        if (z == 0)      { s = Wp;                          K = 512;  N = 1024; }
        else if (z <= 8) { s = Wt + (size_t)(z-1)*DIN*DFF;  K = 1024; N = 512; }
        else             { s = Wc;                          K = 512;  N = 512; }
        const int n0 = bx * 32, k0 = by * 32;
        if (n0 >= N || k0 >= K) return;
        for (int i = ty; i < 32; i += 8)
            tile[i][tx] = s[(size_t)(k0 + i) * N + n0 + tx];
        __syncthreads();
        if (z == 0) {
            for (int i = ty; i < 32; i += 8) {
                int n = n0 + i;
                Wp8[(size_t)n * K + rotk(k0 + tx, n)] = f2fp8(tile[tx][i] * 64.f);
            }
        } else if (z <= 8) {
            unsigned char* d = Wt8 + (size_t)(z-1)*DIN*DFF;
            for (int i = ty; i < 32; i += 8) {
                int n = n0 + i;
                d[(size_t)n * K + rotk(k0 + tx, n)] = f2fp8(tile[tx][i] * 64.f);
            }
        } else {
            for (int i = ty; i < 32; i += 8)
                WcT[(size_t)(n0 + i) * K + k0 + tx] = f2bf(tile[tx][i]);
        }
    } else {
        perm[(b - 26624) * 256 + tid] = -1;
    }
}

// ---- atomic-free scatter: 64 blocks x 512 threads, deterministic placement ----
// totals + padded prefix derived from blockhist alone (no global cnt); block 0
// publishes po[9] for GEMM2. Intra-block rank via LDS atomics only.
__global__ void scatter_kernel(const int* __restrict__ types,
                               const int* __restrict__ blockhist,
                               int* __restrict__ perm,
                               int* __restrict__ invperm,
                               float* __restrict__ outz,
                               int* __restrict__ po_out) {
    __shared__ int tots[8], base[8], fill[8];
    const int blk = blockIdx.x;            // 64
    const int tid = threadIdx.x;           // 512
    const int i = blk * 512 + tid;
    outz[i] = 0.f;
    int pre = 0;
    if (tid < 8) {
        int total = 0;
        for (int j = 0; j < 64; j++) {
            int v = blockhist[j * 8 + tid];
            if (j < blk) pre += v;
            total += v;
        }
        tots[tid] = total;
    }
    __syncthreads();
    if (tid < 8) {
        int off = 0, pob = 0;
        #pragma unroll
        for (int t2 = 0; t2 < 8; t2++) {
            if (t2 == tid) pob = off;
            off += ((tots[t2] + 127) >> 7) << 7;
        }
        base[tid] = pob + pre;
        fill[tid] = 0;
        if (blk == 0) {
            po_out[tid] = pob;
            if (tid == 0) po_out[8] = off;   // off == full padded total for every tid
        }
    }
    __syncthreads();
    const int t = types[i];
    const int r = atomicAdd(&fill[t], 1);  // LDS atomic: intra-block rank
    const int p = base[t] + r;
    perm[p] = i;
    invperm[i] = p;
}

// -- MX-scaled fp8 GEMM: 128x128 tile, BK=128, 4 waves, mfma_scale 32x32x64 ----
// Unit scales (e8m0 0x7F = 2^0) -> numerics identical to non-scaled fp8, but
// 2x MFMA rate and half the instruction count. Wave tile 64x64 = 2x2 of 32x32.
// A-frag: lane holds A[m=lane&31][k=(lane>>5)*32 + 0..32) (32 contiguous bytes
// = one MX scale block). Rotated LDS reads: 4x b64 per frag, all 32 banks.
// Swapped operands -> D[n][tok]: tok = lane&31, n = (reg&3)+8*(reg>>2)+4*kh.
// MODE 0 (GEMM1): A=Xb8 token-order; C = fp8(relu(acc)*0.125) scattered to
//                 bucket position p=invperm[tok], k-rotated by p.
// MODE 1 (GEMM2): A=Xff8 bucket-order (contiguous); B per bucket via po[];
//                 epilogue via perm: Xb[tok] = bf16(Xb[tok]+relu(acc)/512)
template <int MODE>
__global__ __launch_bounds__(256, 4)
void gemm_fp8_kernel(const unsigned char* __restrict__ A,
                     const unsigned char* __restrict__ B,
                     void* __restrict__ Cout,
                     const unsigned short* __restrict__ xres,
                     const int* __restrict__ pmap,   // MODE0: invperm, MODE1: perm
                     const int* __restrict__ po,     // MODE1 only: padded offsets[9]
                     int K, int ldA) {
    __shared__ unsigned char As[128 * 128];
    __shared__ unsigned char Bs[128 * 128];
    __shared__ int ptile[128];

    const int tid  = threadIdx.x;
    const int wave = tid >> 6;
    const int lane = tid & 63;
    const int m32  = lane & 31;
    const int kh   = lane >> 5;          // 0/1
    const int m0 = blockIdx.y * 128;
    const int n0 = blockIdx.x * 128;
    const int wm = (wave & 1) * 64;
    const int wn = (wave >> 1) * 64;

    const unsigned char* Bp = B;
    if constexpr (MODE == 1) {
        if (m0 >= po[8]) return;                  // fully-padded tail block
        int bsel = 0;
        #pragma unroll
        for (int i = 1; i < 8; i++) bsel += (m0 >= po[i]) ? 1 : 0;
        Bp = B + (size_t)bsel * (DIN * DFF);
    }
    if (tid < 128) ptile[tid] = pmap[m0 + tid];

    f32x16 acc[2][2];
    #pragma unroll
    for (int i = 0; i < 2; i++)
        #pragma unroll
        for (int j = 0; j < 2; j++)
            #pragma unroll
            for (int c = 0; c < 16; c++)
                acc[i][j][c] = 0.f;

    for (int k0 = 0; k0 < K; k0 += 128) {
        __syncthreads();
        // A tile [128][128]: 1024 x 16B chunks, 4/thread, LINEAR copy
        #pragma unroll
        for (int i = 0; i < 4; i++) {
            const int c   = (i * 4 + wave) * 64 + lane;
            const int row = c >> 3;
            const int j   = c & 7;
            async16(A + (size_t)(m0 + row) * ldA + k0 + j * 16, (char*)As + (size_t)c * 16);
        }
        // B tile [128][128], linear
        #pragma unroll
        for (int i = 0; i < 4; i++) {
            const int c   = (i * 4 + wave) * 64 + lane;
            const int row = c >> 3;
            const int j   = c & 7;
            async16(Bp + (size_t)(n0 + row) * K + k0 + j * 16, (char*)Bs + (size_t)c * 16);
        }
        __syncthreads();

        #pragma unroll
        for (int ks = 0; ks < 2; ks++) {
            const int j0 = ks * 64 + kh * 32;    // logical byte base in 128B window
            i32x8 af[2], bfr[2];
            #pragma unroll
            for (int mt = 0; mt < 2; mt++) {
                const int r = wm + mt * 32 + m32;
                const int rot = (r & 15) << 3;
                long* pa = (long*)&af[mt];
                #pragma unroll
                for (int u = 0; u < 4; u++)
                    pa[u] = *(const long*)(As + r * 128 + ((j0 + u * 8 + rot) & 127));
            }
            #pragma unroll
            for (int nt = 0; nt < 2; nt++) {
                const int r = wn + nt * 32 + m32;
                const int rot = (r & 15) << 3;
                long* pb = (long*)&bfr[nt];
                #pragma unroll
                for (int u = 0; u < 4; u++)
                    pb[u] = *(const long*)(Bs + r * 128 + ((j0 + u * 8 + rot) & 127));
            }
            #pragma unroll
            for (int mt = 0; mt < 2; mt++)
                #pragma unroll
                for (int nt = 0; nt < 2; nt++)
                    acc[mt][nt] = __builtin_amdgcn_mfma_scale_f32_32x32x64_f8f6f4(
                        bfr[nt], af[mt], acc[mt][nt],
                        0, 0,            // cbsz=fp8, blgp=fp8
                        0, 0x7F,         // opsel_a, scale_a = 2^0
                        0, 0x7F);        // opsel_b, scale_b = 2^0
        }
    }

    // epilogue: lane holds, per frag, 4 groups of 4 consecutive n for token m32
    if constexpr (MODE == 0) {
        unsigned char* C8 = (unsigned char*)Cout;
        #pragma unroll
        for (int mt = 0; mt < 2; mt++) {
            const int p = ptile[wm + mt * 32 + m32];       // bucket position
            const size_t rowbase = (size_t)p * DFF;
            const int prot = (p & 15) << 3;
            #pragma unroll
            for (int nt = 0; nt < 2; nt++) {
                #pragma unroll
                for (int r2 = 0; r2 < 4; r2++) {
                    const int off = n0 + wn + nt * 32 + r2 * 8 + kh * 4;
                    unsigned int pk = pk4_fp8(
                        fmaxf(acc[mt][nt][r2 * 4 + 0], 0.f) * 0.125f,
                        fmaxf(acc[mt][nt][r2 * 4 + 1], 0.f) * 0.125f,
                        fmaxf(acc[mt][nt][r2 * 4 + 2], 0.f) * 0.125f,
                        fmaxf(acc[mt][nt][r2 * 4 + 3], 0.f) * 0.125f);
                    const int phys = (off & ~127) + (((off & 127) + prot) & 127);
                    *(unsigned int*)(C8 + rowbase + phys) = pk;
                }
            }
        }
    } else {
        unsigned short* Cb = (unsigned short*)Cout;
        #pragma unroll
        for (int mt = 0; mt < 2; mt++) {
            int tok = ptile[wm + mt * 32 + m32];
            if (tok < 0) continue;
            const size_t rowbase = (size_t)tok * DIN;
            #pragma unroll
            for (int nt = 0; nt < 2; nt++) {
                #pragma unroll
                for (int r2 = 0; r2 < 4; r2++) {
                    const int ncol = n0 + wn + nt * 32 + r2 * 8 + kh * 4;
                    ushort4 rv = *(const ushort4*)(xres + rowbase + ncol);
                    ushort4 o;
                    o.x = f2bf(bf2f(rv.x) + fmaxf(acc[mt][nt][r2*4+0], 0.f) * 0.001953125f);
                    o.y = f2bf(bf2f(rv.y) + fmaxf(acc[mt][nt][r2*4+1], 0.f) * 0.001953125f);
                    o.z = f2bf(bf2f(rv.z) + fmaxf(acc[mt][nt][r2*4+2], 0.f) * 0.001953125f);
                    o.w = f2bf(bf2f(rv.w) + fmaxf(acc[mt][nt][r2*4+3], 0.f) * 0.001953125f);
                    *(ushort4*)(Cb + rowbase + ncol) = o;
                }
            }
        }
    }
}

// ------- bf16 GEMM3 + head (kept full precision): 128x256 tile, 512 thr --------
// out[tok] += relu(Xb @ W_c1) . w2   (atomicAdd partials per n-block)
__global__ __launch_bounds__(512, 4)
void gemm3_kernel(const unsigned short* __restrict__ A,
                  const unsigned short* __restrict__ B,
                  const float* __restrict__ w2,
                  float* __restrict__ outp,
                  int K, int ldA) {
    __shared__ unsigned short As[128 * 64];
    __shared__ unsigned short Bs[256 * 64];

    const int tid  = threadIdx.x;
    const int wave = tid >> 6;
    const int lane = tid & 63;
    const int quad = lane >> 4;
    const int tl   = lane & 15;
    const int m0 = blockIdx.y * 128;
    const int n0 = blockIdx.x * 256;
    const int wm = (wave & 1) * 64;
    const int wn = (wave >> 1) * 64;

    f32x4 acc[4][4];
    #pragma unroll
    for (int i = 0; i < 4; i++)
        #pragma unroll
        for (int j = 0; j < 4; j++)
            acc[i][j] = (f32x4){0.f, 0.f, 0.f, 0.f};

    for (int k0 = 0; k0 < K; k0 += 64) {
        __syncthreads();
        #pragma unroll
        for (int i = 0; i < 2; i++) {
            const int c   = (i * 8 + wave) * 64 + lane;
            const int row = c >> 3;
            const int gj  = (c & 7) ^ (row & 7);
            async16(A + (size_t)(m0 + row) * ldA + k0 + gj * 8, (char*)As + (size_t)c * 16);
        }
        #pragma unroll
        for (int i = 0; i < 4; i++) {
            const int c   = (i * 8 + wave) * 64 + lane;
            const int row = c >> 3;
            const int gj  = (c & 7) ^ (row & 7);
            async16(B + (size_t)(n0 + row) * K + k0 + gj * 8, (char*)Bs + (size_t)c * 16);
        }
        __syncthreads();

        #pragma unroll
        for (int ks = 0; ks < 2; ks++) {
            bf16x8 af[4], bfr[4];
            const int jc = ks * 4 + quad;
            #pragma unroll
            for (int t = 0; t < 4; t++) {
                const int r = wm + t * 16 + tl;
                af[t] = *(const bf16x8*)(As + (r * 8 + (jc ^ (r & 7))) * 8);
            }
            #pragma unroll
            for (int t = 0; t < 4; t++) {
                const int r = wn + t * 16 + tl;
                bfr[t] = *(const bf16x8*)(Bs + (r * 8 + (jc ^ (r & 7))) * 8);
            }
            #pragma unroll
            for (int mt = 0; mt < 4; mt++)
                #pragma unroll
                for (int nt = 0; nt < 4; nt++)
                    acc[mt][nt] = __builtin_amdgcn_mfma_f32_16x16x32_bf16(
                        bfr[nt], af[mt], acc[mt][nt], 0, 0, 0);
        }
    }

    float4 w2v[4];
    #pragma unroll
    for (int nt = 0; nt < 4; nt++)
        w2v[nt] = *(const float4*)(w2 + n0 + wn + nt * 16 + quad * 4);
    #pragma unroll
    for (int mt = 0; mt < 4; mt++) {
        float s = 0.f;
        #pragma unroll
        for (int nt = 0; nt < 4; nt++) {
            s += fmaxf(acc[mt][nt][0], 0.f) * w2v[nt].x;
            s += fmaxf(acc[mt][nt][1], 0.f) * w2v[nt].y;
            s += fmaxf(acc[mt][nt][2], 0.f) * w2v[nt].z;
            s += fmaxf(acc[mt][nt][3], 0.f) * w2v[nt].w;
        }
        s += __shfl_down(s, 32);
        s += __shfl_down(s, 16);
        if (lane < 16) atomicAdd(&outp[m0 + wm + mt * 16 + lane], s);
    }
}

extern "C" void kernel_launch(void* const* d_in, const int* in_sizes, int n_in,
                              void* d_out, int out_size, void* d_ws, size_t ws_size,
                              hipStream_t stream) {
    const float* x      = (const float*)d_in[0];
    const int*   types  = (const int*)d_in[1];
    const float* W_pre  = (const float*)d_in[2];
    const float* W_types= (const float*)d_in[3];
    const float* W_c1   = (const float*)d_in[4];
    const float* W_c2   = (const float*)d_in[5];
    float* out = (float*)d_out;

    // workspace layout (~91 MB):
    char* ws = (char*)d_ws;
    unsigned short* Xb  = (unsigned short*)(ws);                    // bf16 [32768][512], becomes X_res
    unsigned char*  Xff8= (unsigned char*)(ws + 33554432ull);       // fp8 [MPAD][1024] = 8*x_, bucket order, k-rotated
    unsigned char*  Xb8 = (unsigned char*)(ws + 68157440ull);       // fp8 [32768][512] = x, k-rotated
    unsigned char*  Wp8 = (unsigned char*)(ws + 84934656ull);       // fp8 [1024][512] (x64, rotated)
    unsigned char*  Wt8 = (unsigned char*)(ws + 85458944ull);       // fp8 [8][512][1024] (x64, rotated)
    unsigned short* WcT = (unsigned short*)(ws + 89653248ull);      // bf16 [512][512]
    int* perm           = (int*)(ws + 90177536ull);                  // MPAD ints
    int* invperm        = (int*)(ws + 90312704ull);                  // N_TOK ints
    int* po             = (int*)(ws + 90443776ull);                  // 9 ints (padded offsets)
    int* blockhist      = po + 16;                                   // 64*8 ints

    // 1) merged prep: tokens [0,16384), weights [16384,26624), perm-pad [26624,26756)
    prep_kernel<<<26756, 256, 0, stream>>>(x, Xb, Xb8, types, blockhist,
                                           W_pre, W_types, W_c1, Wp8, Wt8, WcT, perm);
    // 2) deterministic scatter + po publish + out zero
    scatter_kernel<<<64, 512, 0, stream>>>(types, blockhist, perm, invperm, out, po);
    // 3) GEMM1 (MX fp8): Xff8[invperm[tok]] = fp8(8 * relu(x @ W_pre))
    gemm_fp8_kernel<0><<<dim3(DFF / 128, N_TOK / 128), 256, 0, stream>>>(
        Xb8, Wp8, Xff8, nullptr, invperm, nullptr, 512, 512);
    // 4) GEMM2 (MX fp8, routed): Xb = bf16(Xb + relu(Xff8 @ Wt8[bucket]) / 512)
    gemm_fp8_kernel<1><<<dim3(DIN / 128, MPAD / 128), 256, 0, stream>>>(
        Xff8, Wt8, Xb, Xb, perm, po, 1024, 1024);
    // 5) GEMM3 + head (bf16): out = relu(Xb @ W_c1) @ W_c2
    gemm3_kernel<<<dim3(DIN / 256, N_TOK / 128), 512, 0, stream>>>(
        Xb, WcT, W_c2, out, 512, 512);
}

// Round 11
// 230.878 us; speedup vs baseline: 1.2654x; 1.2654x over previous
//
#include <hip/hip_runtime.h>
#include <stdint.h>

// Problem constants (B=64, S=512 -> 32768 tokens)
#define N_TOK 32768
#define DIN   512
#define DFF   1024
#define MPAD  33792   // 32768 + 8*128 worst-case bucket padding

// fp8 rotation convention: within each 128B K-window, row data is rotated by
// (row mod 16)*8 bytes: phys = (k & ~127) + (((k&127) + (row&15)*8) & 127).
// Same permutation on A-rows and B-rows => dot product unchanged. Staging is
// then a linear aligned copy; fragment reads cover all 32 banks (conflict-free).
__device__ __forceinline__ int rotk(int k, int row) {
    return (k & ~127) + (((k & 127) + ((row & 15) << 3)) & 127);
}

typedef __attribute__((ext_vector_type(8))) short bf16x8;
typedef __attribute__((ext_vector_type(4))) float f32x4;

__device__ __forceinline__ unsigned short f2bf(float f) {
    union { float f; unsigned int u; } v; v.f = f;
    unsigned int u = v.u;
    return (unsigned short)((u + 0x7FFFu + ((u >> 16) & 1u)) >> 16);
}
__device__ __forceinline__ float bf2f(unsigned int bits) {
    union { unsigned int u; float f; } v; v.u = bits << 16; return v.f;
}
// pack 4 floats -> 4 OCP e4m3 bytes (hw cvt, saturating)
__device__ __forceinline__ unsigned int pk4_fp8(float a, float b, float c, float d) {
    int v = __builtin_amdgcn_cvt_pk_fp8_f32(a, b, 0, false);
    v = __builtin_amdgcn_cvt_pk_fp8_f32(c, d, v, true);
    return (unsigned int)v;
}
__device__ __forceinline__ unsigned char f2fp8(float a) {
    return (unsigned char)(__builtin_amdgcn_cvt_pk_fp8_f32(a, a, 0, false) & 0xFF);
}

// async 16B global -> LDS (wave-uniform LDS base + lane*16 pattern)
__device__ __forceinline__ void async16(const void* g, void* l) {
    __builtin_amdgcn_global_load_lds(
        (const __attribute__((address_space(1))) void*)g,
        (__attribute__((address_space(3))) void*)l, 16, 0, 0);
}

// ---------------- merged prep: tokens + weights + perm-pad in ONE launch -------
// blocks [0,16384): x -> bf16 Xb + fp8 Xb8 (rotated); blocks 0..63 also
//   histogram their 512 tokens into blockhist[blk][8] (LDS, no global atomics).
// blocks [16384, 26624): weight transpose+cast, z = (b-16384)/1024:
//   z=0: W_pre -> Wp8 [1024][512] fp8 x64 rotated
//   z=1..8: W_types[z-1] -> Wt8 [512][1024] fp8 x64 rotated
//   z=9: W_c1 -> WcT bf16 [512][512] plain
// blocks [26624, 26756): perm[i] = -1 (MPAD entries)
__global__ void prep_kernel(const float* __restrict__ x,
                            unsigned short* __restrict__ Xb,
                            unsigned char* __restrict__ Xb8,
                            const int* __restrict__ types,
                            int* __restrict__ blockhist,
                            const float* __restrict__ Wp,
                            const float* __restrict__ Wt,
                            const float* __restrict__ Wc,
                            unsigned char* __restrict__ Wp8,
                            unsigned char* __restrict__ Wt8,
                            unsigned short* __restrict__ WcT,
                            int* __restrict__ perm) {
    __shared__ float tile[32][33];
    __shared__ int lc[8];
    const int b = blockIdx.x, tid = threadIdx.x;
    if (b < 16384) {
        const int i = b * 1024 + tid * 4;
        float4 v = *(const float4*)(x + i);
        ushort4 o;
        o.x = f2bf(v.x); o.y = f2bf(v.y); o.z = f2bf(v.z); o.w = f2bf(v.w);
        *(ushort4*)(Xb + i) = o;
        const int row = i >> 9;             // DIN=512
        const int k   = i & 511;
        *(unsigned int*)(Xb8 + (size_t)row * DIN + rotk(k, row)) = pk4_fp8(v.x, v.y, v.z, v.w);
        if (b < 64) {
            if (tid < 8) lc[tid] = 0;
            __syncthreads();
            atomicAdd(&lc[types[b * 512 + tid]], 1);
            atomicAdd(&lc[types[b * 512 + 256 + tid]], 1);
            __syncthreads();
            if (tid < 8) blockhist[b * 8 + tid] = lc[tid];
        }
    } else if (b < 26624) {
        const int r = b - 16384;
        const int z = r >> 10;
        const int bx = r & 31, by = (r >> 5) & 31;
        const int tx = tid & 31, ty = tid >> 5;
        const float* s; int K, N;
        if (z == 0)      { s = Wp;                          K = 512;  N = 1024; }
        else if (z <= 8) { s = Wt + (size_t)(z-1)*DIN*DFF;  K = 1024; N = 512; }
        else             { s = Wc;                          K = 512;  N = 512; }
        const int n0 = bx * 32, k0 = by * 32;
        if (n0 >= N || k0 >= K) return;
        for (int i = ty; i < 32; i += 8)
            tile[i][tx] = s[(size_t)(k0 + i) * N + n0 + tx];
        __syncthreads();
        if (z == 0) {
            for (int i = ty; i < 32; i += 8) {
                int n = n0 + i;
                Wp8[(size_t)n * K + rotk(k0 + tx, n)] = f2fp8(tile[tx][i] * 64.f);
            }
        } else if (z <= 8) {
            unsigned char* d = Wt8 + (size_t)(z-1)*DIN*DFF;
            for (int i = ty; i < 32; i += 8) {
                int n = n0 + i;
                d[(size_t)n * K + rotk(k0 + tx, n)] = f2fp8(tile[tx][i] * 64.f);
            }
        } else {
            for (int i = ty; i < 32; i += 8)
                WcT[(size_t)(n0 + i) * K + k0 + tx] = f2bf(tile[tx][i]);
        }
    } else {
        perm[(b - 26624) * 256 + tid] = -1;
    }
}

// ---- atomic-free scatter: 64 blocks x 512 threads, deterministic placement ----
// totals + padded prefix derived from blockhist alone; block 0 publishes po[9]
// for GEMM2. Intra-block rank via LDS atomics only.
__global__ void scatter_kernel(const int* __restrict__ types,
                               const int* __restrict__ blockhist,
                               int* __restrict__ perm,
                               int* __restrict__ invperm,
                               float* __restrict__ outz,
                               int* __restrict__ po_out) {
    __shared__ int tots[8], base[8], fill[8];
    const int blk = blockIdx.x;            // 64
    const int tid = threadIdx.x;           // 512
    const int i = blk * 512 + tid;
    outz[i] = 0.f;
    int pre = 0;
    if (tid < 8) {
        int total = 0;
        for (int j = 0; j < 64; j++) {
            int v = blockhist[j * 8 + tid];
            if (j < blk) pre += v;
            total += v;
        }
        tots[tid] = total;
    }
    __syncthreads();
    if (tid < 8) {
        int off = 0, pob = 0;
        #pragma unroll
        for (int t2 = 0; t2 < 8; t2++) {
            if (t2 == tid) pob = off;
            off += ((tots[t2] + 127) >> 7) << 7;
        }
        base[tid] = pob + pre;
        fill[tid] = 0;
        if (blk == 0) {
            po_out[tid] = pob;
            if (tid == 0) po_out[8] = off;
        }
    }
    __syncthreads();
    const int t = types[i];
    const int r = atomicAdd(&fill[t], 1);  // LDS atomic: intra-block rank
    const int p = base[t] + r;
    perm[p] = i;
    invperm[i] = p;
}

// ---------- fp8 GEMM (r9 proven): 128x128 tile, BK=128, 4 waves, 16x16x32 fp8 --
// Global fp8 data is k-rotated per row (rotk); staging is a LINEAR aligned copy
// (LDS row stride 128B). Fragment read: 8B at (ks*32+quad*8+tl*8)&127 ->
// quarter-wave covers all 32 banks once: conflict-free.
// D[n][tok] via swapped operands: n = quad*4+reg, tok = lane&15.
// MODE 0 (GEMM1): A=Xb8 token-order; C = fp8(relu(acc)*0.125) scattered to
//                 bucket position p=invperm[tok], k-rotated by p.
// MODE 1 (GEMM2): A=Xff8 bucket-order (contiguous); B per bucket via po[];
//                 epilogue via perm: Xb[tok] = bf16(Xb[tok]+relu(acc)/512)
template <int MODE>
__global__ __launch_bounds__(256, 4)
void gemm_fp8_kernel(const unsigned char* __restrict__ A,
                     const unsigned char* __restrict__ B,
                     void* __restrict__ Cout,
                     const unsigned short* __restrict__ xres,
                     const int* __restrict__ pmap,   // MODE0: invperm, MODE1: perm
                     const int* __restrict__ po,     // MODE1 only: padded offsets[9]
                     int K, int ldA) {
    __shared__ unsigned char As[128 * 128];
    __shared__ unsigned char Bs[128 * 128];
    __shared__ int ptile[128];

    const int tid  = threadIdx.x;
    const int wave = tid >> 6;
    const int lane = tid & 63;
    const int quad = lane >> 4;
    const int tl   = lane & 15;
    const int m0 = blockIdx.y * 128;
    const int n0 = blockIdx.x * 128;
    const int wm = (wave & 1) * 64;
    const int wn = (wave >> 1) * 64;

    const unsigned char* Bp = B;
    if constexpr (MODE == 1) {
        if (m0 >= po[8]) return;                  // fully-padded tail block
        int bsel = 0;
        #pragma unroll
        for (int i = 1; i < 8; i++) bsel += (m0 >= po[i]) ? 1 : 0;
        Bp = B + (size_t)bsel * (DIN * DFF);
    }
    if (tid < 128) ptile[tid] = pmap[m0 + tid];

    f32x4 acc[4][4];
    #pragma unroll
    for (int i = 0; i < 4; i++)
        #pragma unroll
        for (int j = 0; j < 4; j++)
            acc[i][j] = (f32x4){0.f, 0.f, 0.f, 0.f};

    for (int k0 = 0; k0 < K; k0 += 128) {
        __syncthreads();
        // A tile [128][128]: 1024 x 16B chunks, 4/thread, LINEAR copy
        #pragma unroll
        for (int i = 0; i < 4; i++) {
            const int c   = (i * 4 + wave) * 64 + lane;
            const int row = c >> 3;
            const int j   = c & 7;
            async16(A + (size_t)(m0 + row) * ldA + k0 + j * 16, (char*)As + (size_t)c * 16);
        }
        // B tile [128][128], linear
        #pragma unroll
        for (int i = 0; i < 4; i++) {
            const int c   = (i * 4 + wave) * 64 + lane;
            const int row = c >> 3;
            const int j   = c & 7;
            async16(Bp + (size_t)(n0 + row) * K + k0 + j * 16, (char*)Bs + (size_t)c * 16);
        }
        __syncthreads();

        #pragma unroll
        for (int ks = 0; ks < 4; ks++) {
            long af[4], bfr[4];
            const int o = (ks * 32 + quad * 8 + tl * 8) & 127;  // rotated frag offset
            #pragma unroll
            for (int t = 0; t < 4; t++)
                af[t] = *(const long*)(As + (wm + t * 16 + tl) * 128 + o);
            #pragma unroll
            for (int t = 0; t < 4; t++)
                bfr[t] = *(const long*)(Bs + (wn + t * 16 + tl) * 128 + o);
            #pragma unroll
            for (int mt = 0; mt < 4; mt++)
                #pragma unroll
                for (int nt = 0; nt < 4; nt++)
                    acc[mt][nt] = __builtin_amdgcn_mfma_f32_16x16x32_fp8_fp8(
                        bfr[nt], af[mt], acc[mt][nt], 0, 0, 0);  // swapped: D[n][tok]
        }
    }

    // epilogue: lane holds 4 consecutive n (regs) for token tl
    if constexpr (MODE == 0) {
        unsigned char* C8 = (unsigned char*)Cout;
        #pragma unroll
        for (int mt = 0; mt < 4; mt++) {
            const int p = ptile[wm + mt * 16 + tl];            // bucket position
            const size_t rowbase = (size_t)p * DFF;
            const int prot = (p & 15) << 3;
            #pragma unroll
            for (int nt = 0; nt < 4; nt++) {
                const int off = wn + nt * 16 + quad * 4;       // in-window offset
                unsigned int pk = pk4_fp8(fmaxf(acc[mt][nt][0], 0.f) * 0.125f,
                                          fmaxf(acc[mt][nt][1], 0.f) * 0.125f,
                                          fmaxf(acc[mt][nt][2], 0.f) * 0.125f,
                                          fmaxf(acc[mt][nt][3], 0.f) * 0.125f);
                const int phys = (off & ~127) + (((off & 127) + prot) & 127);
                *(unsigned int*)(C8 + rowbase + n0 + phys) = pk;
            }
        }
    } else {
        unsigned short* Cb = (unsigned short*)Cout;
        #pragma unroll
        for (int mt = 0; mt < 4; mt++) {
            int tok = ptile[wm + mt * 16 + tl];
            if (tok < 0) continue;
            const size_t rowbase = (size_t)tok * DIN;
            #pragma unroll
            for (int nt = 0; nt < 4; nt++) {
                const int ncol = n0 + wn + nt * 16 + quad * 4;
                ushort4 rv = *(const ushort4*)(xres + rowbase + ncol);
                ushort4 o;
                o.x = f2bf(bf2f(rv.x) + fmaxf(acc[mt][nt][0], 0.f) * 0.001953125f);
                o.y = f2bf(bf2f(rv.y) + fmaxf(acc[mt][nt][1], 0.f) * 0.001953125f);
                o.z = f2bf(bf2f(rv.z) + fmaxf(acc[mt][nt][2], 0.f) * 0.001953125f);
                o.w = f2bf(bf2f(rv.w) + fmaxf(acc[mt][nt][3], 0.f) * 0.001953125f);
                *(ushort4*)(Cb + rowbase + ncol) = o;
            }
        }
    }
}

// ------- bf16 GEMM3 + head (kept full precision): 128x256 tile, 512 thr --------
// out[tok] += relu(Xb @ W_c1) . w2   (atomicAdd partials per n-block)
__global__ __launch_bounds__(512, 4)
void gemm3_kernel(const unsigned short* __restrict__ A,
                  const unsigned short* __restrict__ B,
                  const float* __restrict__ w2,
                  float* __restrict__ outp,
                  int K, int ldA) {
    __shared__ unsigned short As[128 * 64];
    __shared__ unsigned short Bs[256 * 64];

    const int tid  = threadIdx.x;
    const int wave = tid >> 6;
    const int lane = tid & 63;
    const int quad = lane >> 4;
    const int tl   = lane & 15;
    const int m0 = blockIdx.y * 128;
    const int n0 = blockIdx.x * 256;
    const int wm = (wave & 1) * 64;
    const int wn = (wave >> 1) * 64;

    f32x4 acc[4][4];
    #pragma unroll
    for (int i = 0; i < 4; i++)
        #pragma unroll
        for (int j = 0; j < 4; j++)
            acc[i][j] = (f32x4){0.f, 0.f, 0.f, 0.f};

    for (int k0 = 0; k0 < K; k0 += 64) {
        __syncthreads();
        #pragma unroll
        for (int i = 0; i < 2; i++) {
            const int c   = (i * 8 + wave) * 64 + lane;
            const int row = c >> 3;
            const int gj  = (c & 7) ^ (row & 7);
            async16(A + (size_t)(m0 + row) * ldA + k0 + gj * 8, (char*)As + (size_t)c * 16);
        }
        #pragma unroll
        for (int i = 0; i < 4; i++) {
            const int c   = (i * 8 + wave) * 64 + lane;
            const int row = c >> 3;
            const int gj  = (c & 7) ^ (row & 7);
            async16(B + (size_t)(n0 + row) * K + k0 + gj * 8, (char*)Bs + (size_t)c * 16);
        }
        __syncthreads();

        #pragma unroll
        for (int ks = 0; ks < 2; ks++) {
            bf16x8 af[4], bfr[4];
            const int jc = ks * 4 + quad;
            #pragma unroll
            for (int t = 0; t < 4; t++) {
                const int r = wm + t * 16 + tl;
                af[t] = *(const bf16x8*)(As + (r * 8 + (jc ^ (r & 7))) * 8);
            }
            #pragma unroll
            for (int t = 0; t < 4; t++) {
                const int r = wn + t * 16 + tl;
                bfr[t] = *(const bf16x8*)(Bs + (r * 8 + (jc ^ (r & 7))) * 8);
            }
            #pragma unroll
            for (int mt = 0; mt < 4; mt++)
                #pragma unroll
                for (int nt = 0; nt < 4; nt++)
                    acc[mt][nt] = __builtin_amdgcn_mfma_f32_16x16x32_bf16(
                        bfr[nt], af[mt], acc[mt][nt], 0, 0, 0);
        }
    }

    float4 w2v[4];
    #pragma unroll
    for (int nt = 0; nt < 4; nt++)
        w2v[nt] = *(const float4*)(w2 + n0 + wn + nt * 16 + quad * 4);
    #pragma unroll
    for (int mt = 0; mt < 4; mt++) {
        float s = 0.f;
        #pragma unroll
        for (int nt = 0; nt < 4; nt++) {
            s += fmaxf(acc[mt][nt][0], 0.f) * w2v[nt].x;
            s += fmaxf(acc[mt][nt][1], 0.f) * w2v[nt].y;
            s += fmaxf(acc[mt][nt][2], 0.f) * w2v[nt].z;
            s += fmaxf(acc[mt][nt][3], 0.f) * w2v[nt].w;
        }
        s += __shfl_down(s, 32);
        s += __shfl_down(s, 16);
        if (lane < 16) atomicAdd(&outp[m0 + wm + mt * 16 + lane], s);
    }
}

extern "C" void kernel_launch(void* const* d_in, const int* in_sizes, int n_in,
                              void* d_out, int out_size, void* d_ws, size_t ws_size,
                              hipStream_t stream) {
    const float* x      = (const float*)d_in[0];
    const int*   types  = (const int*)d_in[1];
    const float* W_pre  = (const float*)d_in[2];
    const float* W_types= (const float*)d_in[3];
    const float* W_c1   = (const float*)d_in[4];
    const float* W_c2   = (const float*)d_in[5];
    float* out = (float*)d_out;

    // workspace layout (~91 MB):
    char* ws = (char*)d_ws;
    unsigned short* Xb  = (unsigned short*)(ws);                    // bf16 [32768][512], becomes X_res
    unsigned char*  Xff8= (unsigned char*)(ws + 33554432ull);       // fp8 [MPAD][1024] = 8*x_, bucket order, k-rotated
    unsigned char*  Xb8 = (unsigned char*)(ws + 68157440ull);       // fp8 [32768][512] = x, k-rotated
    unsigned char*  Wp8 = (unsigned char*)(ws + 84934656ull);       // fp8 [1024][512] (x64, rotated)
    unsigned char*  Wt8 = (unsigned char*)(ws + 85458944ull);       // fp8 [8][512][1024] (x64, rotated)
    unsigned short* WcT = (unsigned short*)(ws + 89653248ull);      // bf16 [512][512]
    int* perm           = (int*)(ws + 90177536ull);                  // MPAD ints
    int* invperm        = (int*)(ws + 90312704ull);                  // N_TOK ints
    int* po             = (int*)(ws + 90443776ull);                  // 9 ints (padded offsets)
    int* blockhist      = po + 16;                                   // 64*8 ints

    // 1) merged prep: tokens [0,16384), weights [16384,26624), perm-pad [26624,26756)
    prep_kernel<<<26756, 256, 0, stream>>>(x, Xb, Xb8, types, blockhist,
                                           W_pre, W_types, W_c1, Wp8, Wt8, WcT, perm);
    // 2) deterministic scatter + po publish + out zero
    scatter_kernel<<<64, 512, 0, stream>>>(types, blockhist, perm, invperm, out, po);
    // 3) GEMM1 (fp8): Xff8[invperm[tok]] = fp8(8 * relu(x @ W_pre))
    gemm_fp8_kernel<0><<<dim3(DFF / 128, N_TOK / 128), 256, 0, stream>>>(
        Xb8, Wp8, Xff8, nullptr, invperm, nullptr, 512, 512);
    // 4) GEMM2 (fp8, routed): Xb = bf16(Xb + relu(Xff8 @ Wt8[bucket]) / 512)
    gemm_fp8_kernel<1><<<dim3(DIN / 128, MPAD / 128), 256, 0, stream>>>(
        Xff8, Wt8, Xb, Xb, perm, po, 1024, 1024);
    // 5) GEMM3 + head (bf16): out = relu(Xb @ W_c1) @ W_c2
    gemm3_kernel<<<dim3(DIN / 256, N_TOK / 128), 512, 0, stream>>>(
        Xb, WcT, W_c2, out, 512, 512);
}